// Round 2
// baseline (4017.244 us; speedup 1.0000x reference)
//
#include <hip/hip_runtime.h>
#include <hip/hip_bf16.h>

#define DH 256
#define DE 32
#define NLAYERS 5
#define NEG_SLOPE 0.2f
#define EPSV 1e-16f

// ---------------------------------------------------------------- utilities
__global__ void k_count(const int* __restrict__ dst, int* __restrict__ cnt, int E) {
    int e = blockIdx.x * 256 + threadIdx.x;
    if (e < E) atomicAdd(&cnt[dst[e]], 1);
}

// single-block exclusive scan of cnt -> off, plus inv_deg
__global__ void k_scan(const int* __restrict__ cnt, int* __restrict__ off,
                       float* __restrict__ inv_deg, int n, int total) {
    __shared__ int sums[1024];
    int t = threadIdx.x;
    int chunk = (n + 1023) >> 10;
    int s0 = t * chunk, s1 = min(s0 + chunk, n);
    int s = 0;
    for (int i = s0; i < s1; ++i) s += cnt[i];
    sums[t] = s;
    __syncthreads();
    for (int d = 1; d < 1024; d <<= 1) {
        int v = (t >= d) ? sums[t - d] : 0;
        __syncthreads();
        sums[t] += v;
        __syncthreads();
    }
    int run = (t == 0) ? 0 : sums[t - 1];
    for (int i = s0; i < s1; ++i) {
        off[i] = run;
        int c = cnt[i];
        run += c;
        inv_deg[i] = 1.0f / (float)max(c, 1);
    }
    if (t == 0) off[n] = total;
}

__global__ void k_fill(const int* __restrict__ src, const int* __restrict__ dst,
                       const int* __restrict__ off, int* __restrict__ cur,
                       int* __restrict__ csrc, int* __restrict__ ceid, int E) {
    int e = blockIdx.x * 256 + threadIdx.x;
    if (e >= E) return;
    int d = dst[e];
    int p = off[d] + atomicAdd(&cur[d], 1);
    csrc[p] = src[e];
    ceid[p] = e;
}

// we_ae[l][d] = sum_j We[l,d,j] * a_e[l,j]   (5*32 dots of length 256)
__global__ void k_we_ae(const float* __restrict__ We, const float* __restrict__ a_e,
                        float* __restrict__ out) {
    int t = threadIdx.x;
    if (t >= NLAYERS * DE) return;
    int l = t >> 5, d = t & 31;
    const float* w = We + ((size_t)l * DE + d) * DH;
    const float* ae = a_e + (size_t)l * DH;
    float s = 0.f;
    for (int j = 0; j < DH; ++j) s += w[j] * ae[j];
    out[t] = s;
}

// elog[l][e] = edge_attr[e,:] . we_ae[l,:]
__global__ void k_elogit(const float* __restrict__ ea, const float* __restrict__ we_ae,
                         float* __restrict__ elog, int E) {
    __shared__ float w[NLAYERS * DE];
    if (threadIdx.x < NLAYERS * DE) w[threadIdx.x] = we_ae[threadIdx.x];
    __syncthreads();
    int e = blockIdx.x * 256 + threadIdx.x;
    if (e >= E) return;
    const float4* p = (const float4*)(ea + (size_t)e * DE);
    float r[NLAYERS] = {0, 0, 0, 0, 0};
    #pragma unroll
    for (int i = 0; i < DE / 4; ++i) {
        float4 x = p[i];
        #pragma unroll
        for (int l = 0; l < NLAYERS; ++l) {
            r[l] += x.x * w[l * DE + i * 4 + 0] + x.y * w[l * DE + i * 4 + 1] +
                    x.z * w[l * DE + i * 4 + 2] + x.w * w[l * DE + i * 4 + 3];
        }
    }
    #pragma unroll
    for (int l = 0; l < NLAYERS; ++l) elog[(size_t)l * E + e] = r[l];
}

// h = x @ W0 + b0   (K=3)
__global__ void k_lin0(const float* __restrict__ x, const float* __restrict__ W0,
                       const float* __restrict__ b0, float* __restrict__ h, int n) {
    int node = blockIdx.x;
    int c = threadIdx.x;
    if (node >= n) return;
    float x0 = x[(size_t)node * 3 + 0];
    float x1 = x[(size_t)node * 3 + 1];
    float x2 = x[(size_t)node * 3 + 2];
    h[(size_t)node * DH + c] = b0[c] + x0 * W0[c] + x1 * W0[DH + c] + x2 * W0[2 * DH + c];
}

// per-node dots: s_src[n] = hg[n,:].a_src ; s_dst[n] = hg[n,:].a_dst  (wave per row)
__global__ void k_dots(const float* __restrict__ hg, const float* __restrict__ asrc,
                       const float* __restrict__ adst, float* __restrict__ ssrc,
                       float* __restrict__ sdst, int n) {
    int wave = threadIdx.x >> 6, lane = threadIdx.x & 63;
    int row = blockIdx.x * 4 + wave;
    if (row >= n) return;
    const float* r = hg + (size_t)row * DH;
    float a = 0.f, b = 0.f;
    for (int i = lane; i < DH; i += 64) {
        float v = r[i];
        a += v * asrc[i];
        b += v * adst[i];
    }
    for (int d = 32; d; d >>= 1) { a += __shfl_down(a, d); b += __shfl_down(b, d); }
    if (lane == 0) { ssrc[row] = a; sdst[row] = b; }
}

// per-edge leaky-relu logit
__global__ void k_logit(const float* __restrict__ ssrc, const float* __restrict__ sdst,
                        const int* __restrict__ src, const int* __restrict__ dst,
                        const float* __restrict__ elog, float* __restrict__ logit, int E) {
    int e = blockIdx.x * 256 + threadIdx.x;
    if (e >= E) return;
    float raw = ssrc[src[e]] + sdst[dst[e]] + elog[e];
    logit[e] = raw > 0.f ? raw : NEG_SLOPE * raw;
}

// segment softmax per dst node over CSR; writes alpha at CSR position
__global__ void k_softmax(const int* __restrict__ off, const int* __restrict__ ceid,
                          const float* __restrict__ logit, float* __restrict__ alpha, int n) {
    int wave = threadIdx.x >> 6, lane = threadIdx.x & 63;
    int node = blockIdx.x * 4 + wave;
    if (node >= n) return;
    int p0 = off[node], p1 = off[node + 1];
    float m = -3.4e38f;
    for (int p = p0 + lane; p < p1; p += 64) m = fmaxf(m, logit[ceid[p]]);
    for (int d = 32; d; d >>= 1) m = fmaxf(m, __shfl_xor(m, d));
    float s = 0.f;
    for (int p = p0 + lane; p < p1; p += 64) s += expf(logit[ceid[p]] - m);
    for (int d = 32; d; d >>= 1) s += __shfl_xor(s, d);
    float inv = 1.0f / (s + EPSV);
    for (int p = p0 + lane; p < p1; p += 64) alpha[p] = expf(logit[ceid[p]] - m) * inv;
}

// agg[n,c] = relu( sum_p alpha[p]*hg[csrc[p],c] + bg[c] )   one block per node
__global__ void k_agg(const int* __restrict__ off, const int* __restrict__ csrc,
                      const float* __restrict__ alpha, const float* __restrict__ hg,
                      const float* __restrict__ bias, float* __restrict__ h1, int n) {
    int node = blockIdx.x;
    int c = threadIdx.x;
    if (node >= n) return;
    int p0 = off[node], p1 = off[node + 1];
    float acc = 0.f;
    for (int p = p0; p < p1; ++p) {
        int s = csrc[p];
        float a = alpha[p];
        acc += a * hg[(size_t)s * DH + c];
    }
    float v = acc + bias[c];
    h1[(size_t)node * DH + c] = v > 0.f ? v : 0.f;
}

// mean[n,c] = (sum_p h1[csrc[p],c]) * inv_deg[n]
__global__ void k_mean(const int* __restrict__ off, const int* __restrict__ csrc,
                       const float* __restrict__ h1, const float* __restrict__ inv_deg,
                       float* __restrict__ mean, int n) {
    int node = blockIdx.x;
    int c = threadIdx.x;
    if (node >= n) return;
    int p0 = off[node], p1 = off[node + 1];
    float acc = 0.f;
    for (int p = p0; p < p1; ++p) acc += h1[(size_t)csrc[p] * DH + c];
    mean[(size_t)node * DH + c] = acc * inv_deg[node];
}

// out[n] = h[n,:] . W1 + b1
__global__ void k_out(const float* __restrict__ h, const float* __restrict__ W1,
                      const float* __restrict__ b1, float* __restrict__ out, int n) {
    int wave = threadIdx.x >> 6, lane = threadIdx.x & 63;
    int row = blockIdx.x * 4 + wave;
    if (row >= n) return;
    const float* r = h + (size_t)row * DH;
    float s = 0.f;
    for (int i = lane; i < DH; i += 64) s += r[i] * W1[i];
    for (int d = 32; d; d >>= 1) s += __shfl_down(s, d);
    if (lane == 0) out[row] = s + b1[0];
}

// ------------------------------------------------------------------ GEMM
// C[M,256] = epilogue( A@B (+ A2@B2) + bias ) (+ resid)
// 128x128 tile, BK=32, 256 threads, 8x8 per thread.
template <int TWO, int HASBIAS, int RELU, int RESID>
__global__ __launch_bounds__(256) void k_gemm(
    const float* __restrict__ A, const float* __restrict__ B,
    const float* __restrict__ A2, const float* __restrict__ B2,
    const float* __restrict__ bias, const float* __restrict__ resid,
    float* __restrict__ C, int M) {
    __shared__ __align__(16) float Ast[32][128];  // [kk][row]
    __shared__ __align__(16) float Bst[32][128];  // [kk][col]
    const int t = threadIdx.x;
    const int tx = t & 15, ty = t >> 4;
    const int bm = blockIdx.x * 128;
    const int bn = blockIdx.y * 128;
    float acc[8][8] = {};

    for (int pass = 0; pass < (TWO ? 2 : 1); ++pass) {
        const float* Ap = pass ? A2 : A;
        const float* Bp = pass ? B2 : B;
        for (int k0 = 0; k0 < DH; k0 += 32) {
            // ---- stage A (transposed) and B tiles
            #pragma unroll
            for (int i = 0; i < 4; ++i) {
                int q = t + i * 256;        // f4 index among 1024
                int row = q >> 3, kf = q & 7;
                int grow = bm + row;
                float4 v = make_float4(0.f, 0.f, 0.f, 0.f);
                if (grow < M) v = *(const float4*)(Ap + (size_t)grow * DH + k0 + kf * 4);
                Ast[kf * 4 + 0][row] = v.x;
                Ast[kf * 4 + 1][row] = v.y;
                Ast[kf * 4 + 2][row] = v.z;
                Ast[kf * 4 + 3][row] = v.w;
            }
            #pragma unroll
            for (int i = 0; i < 4; ++i) {
                int q = t + i * 256;
                int kk = q >> 5, cf = q & 31;
                float4 v = *(const float4*)(Bp + (size_t)(k0 + kk) * DH + bn + cf * 4);
                *(float4*)&Bst[kk][cf * 4] = v;
            }
            __syncthreads();
            // ---- compute
            #pragma unroll
            for (int kb = 0; kb < 8; ++kb) {
                #pragma unroll
                for (int kq = 0; kq < 4; ++kq) {
                    int kk = kb * 4 + kq;
                    float4 a0 = *(const float4*)&Ast[kk][ty * 8];
                    float4 a1 = *(const float4*)&Ast[kk][ty * 8 + 4];
                    float4 b0 = *(const float4*)&Bst[kk][tx * 8];
                    float4 b1 = *(const float4*)&Bst[kk][tx * 8 + 4];
                    float a[8] = {a0.x, a0.y, a0.z, a0.w, a1.x, a1.y, a1.z, a1.w};
                    float b[8] = {b0.x, b0.y, b0.z, b0.w, b1.x, b1.y, b1.z, b1.w};
                    #pragma unroll
                    for (int i = 0; i < 8; ++i)
                        #pragma unroll
                        for (int j = 0; j < 8; ++j)
                            acc[i][j] = fmaf(a[i], b[j], acc[i][j]);
                }
            }
            __syncthreads();
        }
    }
    // ---- epilogue
    #pragma unroll
    for (int i = 0; i < 8; ++i) {
        int row = bm + ty * 8 + i;
        if (row >= M) continue;
        size_t base = (size_t)row * DH + bn + tx * 8;
        #pragma unroll
        for (int jc = 0; jc < 2; ++jc) {
            float v0 = acc[i][jc * 4 + 0], v1 = acc[i][jc * 4 + 1];
            float v2 = acc[i][jc * 4 + 2], v3 = acc[i][jc * 4 + 3];
            if (HASBIAS) {
                int col = bn + tx * 8 + jc * 4;
                v0 += bias[col + 0]; v1 += bias[col + 1];
                v2 += bias[col + 2]; v3 += bias[col + 3];
            }
            if (RELU) {
                v0 = fmaxf(v0, 0.f); v1 = fmaxf(v1, 0.f);
                v2 = fmaxf(v2, 0.f); v3 = fmaxf(v3, 0.f);
            }
            if (RESID) {
                float4 r = *(const float4*)(resid + base + jc * 4);
                v0 += r.x; v1 += r.y; v2 += r.z; v3 += r.w;
            }
            float4 o = make_float4(v0, v1, v2, v3);
            *(float4*)(C + base + jc * 4) = o;
        }
    }
}

// ------------------------------------------------------------------ launch
extern "C" void kernel_launch(void* const* d_in, const int* in_sizes, int n_in,
                              void* d_out, int out_size, void* d_ws, size_t ws_size,
                              hipStream_t stream) {
    const float* x    = (const float*)d_in[0];
    const int*   ei   = (const int*)d_in[1];
    const float* ea   = (const float*)d_in[2];
    const float* W0   = (const float*)d_in[3];
    const float* b0   = (const float*)d_in[4];
    const float* W1   = (const float*)d_in[5];
    const float* b1   = (const float*)d_in[6];
    const float* Wg   = (const float*)d_in[7];
    const float* bg   = (const float*)d_in[8];
    const float* a_src= (const float*)d_in[9];
    const float* a_dst= (const float*)d_in[10];
    const float* We   = (const float*)d_in[11];
    const float* a_e  = (const float*)d_in[12];
    const float* Ws   = (const float*)d_in[13];
    const float* Wn   = (const float*)d_in[14];
    const float* bm   = (const float*)d_in[15];
    float* out = (float*)d_out;

    const int N = in_sizes[0] / 3;
    const int E = in_sizes[1] / 2;
    const int* srcI = ei;
    const int* dstI = ei + E;

    // ---- workspace carve-up
    char* p = (char*)d_ws;
    auto alloc = [&](size_t bytes) {
        void* r = (void*)p;
        p += (bytes + 255) & ~(size_t)255;
        return r;
    };
    size_t NB = (size_t)N * DH * sizeof(float);
    float* big[4];
    for (int i = 0; i < 4; ++i) big[i] = (float*)alloc(NB);
    float* elog  = (float*)alloc((size_t)NLAYERS * E * sizeof(float));
    float* logit = (float*)alloc((size_t)E * sizeof(float));
    float* alpha = (float*)alloc((size_t)E * sizeof(float));
    int*   csrc  = (int*)alloc((size_t)E * sizeof(int));
    int*   ceid  = (int*)alloc((size_t)E * sizeof(int));
    int*   off   = (int*)alloc((size_t)(N + 1) * sizeof(int));
    int*   cnt   = (int*)alloc((size_t)N * sizeof(int));
    int*   cur   = (int*)alloc((size_t)N * sizeof(int));
    float* invd  = (float*)alloc((size_t)N * sizeof(float));
    float* ssrc  = (float*)alloc((size_t)N * sizeof(float));
    float* sdst  = (float*)alloc((size_t)N * sizeof(float));
    float* weae  = (float*)alloc((size_t)NLAYERS * DE * sizeof(float));

    const int EB = (E + 255) / 256;
    const int NB4 = (N + 3) / 4;
    const int MB = (N + 127) / 128;

    // ---- CSR build (once per call)
    hipMemsetAsync(cnt, 0, (size_t)N * sizeof(int), stream);
    hipMemsetAsync(cur, 0, (size_t)N * sizeof(int), stream);
    k_count<<<EB, 256, 0, stream>>>(dstI, cnt, E);
    k_scan<<<1, 1024, 0, stream>>>(cnt, off, invd, N, E);
    k_fill<<<EB, 256, 0, stream>>>(srcI, dstI, off, cur, csrc, ceid, E);

    // ---- h-independent edge terms for all layers
    k_we_ae<<<1, 256, 0, stream>>>(We, a_e, weae);
    k_elogit<<<EB, 256, 0, stream>>>(ea, weae, elog, E);

    // ---- input projection
    k_lin0<<<N, DH, 0, stream>>>(x, W0, b0, big[0], N);

    // ---- residual blocks
    float* H = big[0];
    float* freeb[3] = {big[1], big[2], big[3]};
    for (int l = 0; l < NLAYERS; ++l) {
        float* hg = freeb[0];
        float* h1 = freeb[1];
        float* hn = freeb[2];
        float* mean = hg;  // reuse after k_agg
        const float* Wg_l = Wg + (size_t)l * DH * DH;
        const float* Ws_l = Ws + (size_t)l * DH * DH;
        const float* Wn_l = Wn + (size_t)l * DH * DH;

        k_gemm<0, 0, 0, 0><<<dim3(MB, 2), 256, 0, stream>>>(
            H, Wg_l, nullptr, nullptr, nullptr, nullptr, hg, N);
        k_dots<<<NB4, 256, 0, stream>>>(hg, a_src + (size_t)l * DH, a_dst + (size_t)l * DH,
                                        ssrc, sdst, N);
        k_logit<<<EB, 256, 0, stream>>>(ssrc, sdst, srcI, dstI, elog + (size_t)l * E, logit, E);
        k_softmax<<<NB4, 256, 0, stream>>>(off, ceid, logit, alpha, N);
        k_agg<<<N, DH, 0, stream>>>(off, csrc, alpha, hg, bg + (size_t)l * DH, h1, N);
        k_mean<<<N, DH, 0, stream>>>(off, csrc, h1, invd, mean, N);
        k_gemm<1, 1, 1, 1><<<dim3(MB, 2), 256, 0, stream>>>(
            h1, Ws_l, mean, Wn_l, bm + (size_t)l * DH, H, hn, N);

        freeb[0] = H;
        freeb[1] = hg;
        freeb[2] = h1;
        H = hn;
    }

    // ---- output projection
    k_out<<<NB4, 256, 0, stream>>>(H, W1, b1, out, N);
}

// Round 3
// 2084.332 us; speedup vs baseline: 1.9274x; 1.9274x over previous
//
#include <hip/hip_runtime.h>
#include <hip/hip_bf16.h>

#define DH 256
#define DE 32
#define NLAYERS 5
#define NEG_SLOPE 0.2f
#define EPSV 1e-16f

typedef __attribute__((ext_vector_type(8))) short bf16x8;
typedef __attribute__((ext_vector_type(4))) float f32x4;

__device__ inline float bf2f(unsigned short u) {
    unsigned x = ((unsigned)u) << 16;
    union { unsigned u; float f; } c; c.u = x; return c.f;
}
__device__ inline unsigned short f2bf(float f) {
    union { float f; unsigned u; } c; c.f = f;
    unsigned b = c.u;
    unsigned r = (b + 0x7FFF + ((b >> 16) & 1)) >> 16;
    return (unsigned short)r;
}

// ---------------------------------------------------------------- CSR build
__global__ void k_count(const int* __restrict__ dst, int* __restrict__ cnt, int E) {
    int e = blockIdx.x * 256 + threadIdx.x;
    if (e < E) atomicAdd(&cnt[dst[e]], 1);
}

__global__ void k_scan(const int* __restrict__ cnt, int* __restrict__ off,
                       float* __restrict__ inv_deg, int n, int total) {
    __shared__ int sums[1024];
    int t = threadIdx.x;
    int chunk = (n + 1023) >> 10;
    int s0 = t * chunk, s1 = min(s0 + chunk, n);
    int s = 0;
    for (int i = s0; i < s1; ++i) s += cnt[i];
    sums[t] = s;
    __syncthreads();
    for (int d = 1; d < 1024; d <<= 1) {
        int v = (t >= d) ? sums[t - d] : 0;
        __syncthreads();
        sums[t] += v;
        __syncthreads();
    }
    int run = (t == 0) ? 0 : sums[t - 1];
    for (int i = s0; i < s1; ++i) {
        off[i] = run;
        int c = cnt[i];
        run += c;
        inv_deg[i] = 1.0f / (float)max(c, 1);
    }
    if (t == 0) off[n] = total;
}

__global__ void k_fill(const int* __restrict__ src, const int* __restrict__ dst,
                       const int* __restrict__ off, int* __restrict__ cur,
                       int* __restrict__ csrc, int* __restrict__ ceid, int E) {
    int e = blockIdx.x * 256 + threadIdx.x;
    if (e >= E) return;
    int d = dst[e];
    int p = off[d] + atomicAdd(&cur[d], 1);
    csrc[p] = src[e];
    ceid[p] = e;
}

// ---------------------------------------------------------------- edge precompute
__global__ void k_we_ae(const float* __restrict__ We, const float* __restrict__ a_e,
                        float* __restrict__ out) {
    int t = threadIdx.x;
    if (t >= NLAYERS * DE) return;
    int l = t >> 5, d = t & 31;
    const float* w = We + ((size_t)l * DE + d) * DH;
    const float* ae = a_e + (size_t)l * DH;
    float s = 0.f;
    for (int j = 0; j < DH; ++j) s += w[j] * ae[j];
    out[t] = s;
}

__global__ void k_elogit(const float* __restrict__ ea, const float* __restrict__ we_ae,
                         float* __restrict__ elog, int E) {
    __shared__ float w[NLAYERS * DE];
    if (threadIdx.x < NLAYERS * DE) w[threadIdx.x] = we_ae[threadIdx.x];
    __syncthreads();
    int e = blockIdx.x * 256 + threadIdx.x;
    if (e >= E) return;
    const float4* p = (const float4*)(ea + (size_t)e * DE);
    float r[NLAYERS] = {0, 0, 0, 0, 0};
    #pragma unroll
    for (int i = 0; i < DE / 4; ++i) {
        float4 x = p[i];
        #pragma unroll
        for (int l = 0; l < NLAYERS; ++l) {
            r[l] += x.x * w[l * DE + i * 4 + 0] + x.y * w[l * DE + i * 4 + 1] +
                    x.z * w[l * DE + i * 4 + 2] + x.w * w[l * DE + i * 4 + 3];
        }
    }
    #pragma unroll
    for (int l = 0; l < NLAYERS; ++l) elog[(size_t)l * E + e] = r[l];
}

// ---------------------------------------------------------------- weight transpose fp32 -> bf16
// Wt[z][col][row] = W[z][row][col]; z: 0-4 Wg, 5-9 Ws, 10-14 Wn
__global__ void k_wt(const float* __restrict__ Wg, const float* __restrict__ Ws,
                     const float* __restrict__ Wn, unsigned short* __restrict__ Wt) {
    __shared__ float tile[32][33];
    int z = blockIdx.z;
    const float* W = z < 5 ? Wg + (size_t)z * DH * DH
                   : (z < 10 ? Ws + (size_t)(z - 5) * DH * DH
                             : Wn + (size_t)(z - 10) * DH * DH);
    unsigned short* out = Wt + (size_t)z * DH * DH;
    int c0 = blockIdx.x * 32, r0 = blockIdx.y * 32;
    int tx = threadIdx.x, ty = threadIdx.y;
    for (int j = ty; j < 32; j += 8) tile[j][tx] = W[(size_t)(r0 + j) * DH + c0 + tx];
    __syncthreads();
    for (int j = ty; j < 32; j += 8)
        out[(size_t)(c0 + j) * DH + r0 + tx] = f2bf(tile[tx][j]);
}

// ---------------------------------------------------------------- lin0 (fp32 + bf16 out)
__global__ void k_lin0(const float* __restrict__ x, const float* __restrict__ W0,
                       const float* __restrict__ b0, float* __restrict__ hf,
                       unsigned short* __restrict__ hb, int n) {
    int node = blockIdx.x;
    int c = threadIdx.x;
    if (node >= n) return;
    float x0 = x[(size_t)node * 3 + 0];
    float x1 = x[(size_t)node * 3 + 1];
    float x2 = x[(size_t)node * 3 + 2];
    float v = b0[c] + x0 * W0[c] + x1 * W0[DH + c] + x2 * W0[2 * DH + c];
    hf[(size_t)node * DH + c] = v;
    hb[(size_t)node * DH + c] = f2bf(v);
}

// ---------------------------------------------------------------- per-node dots (bf16 input)
__global__ void k_dots(const unsigned short* __restrict__ hg, const float* __restrict__ asrc,
                       const float* __restrict__ adst, float* __restrict__ ssrc,
                       float* __restrict__ sdst, int n) {
    int wave = threadIdx.x >> 6, lane = threadIdx.x & 63;
    int row = blockIdx.x * 4 + wave;
    if (row >= n) return;
    ushort4 v = *(const ushort4*)(hg + (size_t)row * DH + lane * 4);
    float4 wa = *(const float4*)(asrc + lane * 4);
    float4 wb = *(const float4*)(adst + lane * 4);
    float f0 = bf2f(v.x), f1 = bf2f(v.y), f2 = bf2f(v.z), f3 = bf2f(v.w);
    float a = f0 * wa.x + f1 * wa.y + f2 * wa.z + f3 * wa.w;
    float b = f0 * wb.x + f1 * wb.y + f2 * wb.z + f3 * wb.w;
    for (int d = 32; d; d >>= 1) { a += __shfl_down(a, d); b += __shfl_down(b, d); }
    if (lane == 0) { ssrc[row] = a; sdst[row] = b; }
}

// ---------------------------------------------------------------- per-edge logit
__global__ void k_logit(const float* __restrict__ ssrc, const float* __restrict__ sdst,
                        const int* __restrict__ src, const int* __restrict__ dst,
                        const float* __restrict__ elog, float* __restrict__ logit, int E) {
    int e = blockIdx.x * 256 + threadIdx.x;
    if (e >= E) return;
    float raw = ssrc[src[e]] + sdst[dst[e]] + elog[e];
    logit[e] = raw > 0.f ? raw : NEG_SLOPE * raw;
}

// ---------------------------------------------------------------- segment softmax
__global__ void k_softmax(const int* __restrict__ off, const int* __restrict__ ceid,
                          const float* __restrict__ logit, float* __restrict__ alpha, int n) {
    int wave = threadIdx.x >> 6, lane = threadIdx.x & 63;
    int node = blockIdx.x * 4 + wave;
    if (node >= n) return;
    int p0 = off[node], p1 = off[node + 1];
    float m = -3.4e38f;
    for (int p = p0 + lane; p < p1; p += 64) m = fmaxf(m, logit[ceid[p]]);
    for (int d = 32; d; d >>= 1) m = fmaxf(m, __shfl_xor(m, d));
    float s = 0.f;
    for (int p = p0 + lane; p < p1; p += 64) s += expf(logit[ceid[p]] - m);
    for (int d = 32; d; d >>= 1) s += __shfl_xor(s, d);
    float inv = 1.0f / (s + EPSV);
    for (int p = p0 + lane; p < p1; p += 64) alpha[p] = expf(logit[ceid[p]] - m) * inv;
}

// ---------------------------------------------------------------- GAT aggregate (bf16 gather, wave/node)
__global__ void k_agg(const int* __restrict__ off, const int* __restrict__ csrc,
                      const float* __restrict__ alpha, const unsigned short* __restrict__ hg,
                      const float* __restrict__ bias, unsigned short* __restrict__ h1, int n) {
    int wave = threadIdx.x >> 6, lane = threadIdx.x & 63;
    int node = blockIdx.x * 4 + wave;
    if (node >= n) return;
    int p0 = off[node], p1 = off[node + 1];
    int c = lane * 4;
    float a0 = 0.f, a1 = 0.f, a2 = 0.f, a3 = 0.f;
    for (int p = p0; p < p1; ++p) {
        float a = alpha[p];
        ushort4 v = *(const ushort4*)(hg + (size_t)csrc[p] * DH + c);
        a0 += a * bf2f(v.x); a1 += a * bf2f(v.y);
        a2 += a * bf2f(v.z); a3 += a * bf2f(v.w);
    }
    float4 bb = *(const float4*)(bias + c);
    ushort4 o;
    o.x = f2bf(fmaxf(a0 + bb.x, 0.f));
    o.y = f2bf(fmaxf(a1 + bb.y, 0.f));
    o.z = f2bf(fmaxf(a2 + bb.z, 0.f));
    o.w = f2bf(fmaxf(a3 + bb.w, 0.f));
    *(ushort4*)(h1 + (size_t)node * DH + c) = o;
}

// ---------------------------------------------------------------- mean aggregate (bf16 gather)
__global__ void k_mean(const int* __restrict__ off, const int* __restrict__ csrc,
                       const unsigned short* __restrict__ h1, const float* __restrict__ inv_deg,
                       unsigned short* __restrict__ mean, int n) {
    int wave = threadIdx.x >> 6, lane = threadIdx.x & 63;
    int node = blockIdx.x * 4 + wave;
    if (node >= n) return;
    int p0 = off[node], p1 = off[node + 1];
    int c = lane * 4;
    float a0 = 0.f, a1 = 0.f, a2 = 0.f, a3 = 0.f;
    for (int p = p0; p < p1; ++p) {
        ushort4 v = *(const ushort4*)(h1 + (size_t)csrc[p] * DH + c);
        a0 += bf2f(v.x); a1 += bf2f(v.y); a2 += bf2f(v.z); a3 += bf2f(v.w);
    }
    float inv = inv_deg[node];
    ushort4 o;
    o.x = f2bf(a0 * inv); o.y = f2bf(a1 * inv);
    o.z = f2bf(a2 * inv); o.w = f2bf(a3 * inv);
    *(ushort4*)(mean + (size_t)node * DH + c) = o;
}

// ---------------------------------------------------------------- final projection
__global__ void k_out(const float* __restrict__ h, const float* __restrict__ W1,
                      const float* __restrict__ b1, float* __restrict__ out, int n) {
    int wave = threadIdx.x >> 6, lane = threadIdx.x & 63;
    int row = blockIdx.x * 4 + wave;
    if (row >= n) return;
    const float* r = h + (size_t)row * DH;
    float s = 0.f;
    for (int i = lane; i < DH; i += 64) s += r[i] * W1[i];
    for (int d = 32; d; d >>= 1) s += __shfl_down(s, d);
    if (lane == 0) out[row] = s + b1[0];
}

// ---------------------------------------------------------------- MFMA GEMM
// C[M,256] = (A@B) [+ A2@B2] with optional epilogue (bias, relu, +resid fp32).
// A: [Mpad][256] bf16 row-major; Bt: [256][256] bf16 = B^T row-major.
// Block 128x128 (2x2 waves, 64x64 per wave). No LDS: direct global fragment loads.
// mfma_f32_16x16x32_bf16 frag layout: A/B lane l holds 8 contiguous k at
// row/col = l&15, k0 = (l>>4)*8; C/D: col = l&15, row = (l>>4)*4 + reg.
template <int TWO, int EPI>
__global__ __launch_bounds__(256) void k_gemm_mfma(
    const unsigned short* __restrict__ A, const unsigned short* __restrict__ Bt,
    const unsigned short* __restrict__ A2, const unsigned short* __restrict__ B2t,
    const float* __restrict__ bias, const float* __restrict__ resid,
    float* __restrict__ Cf, unsigned short* __restrict__ Cb, int M) {
    const int t = threadIdx.x;
    const int wid = t >> 6, lane = t & 63;
    const int wr = wid >> 1, wc = wid & 1;
    const int bm = blockIdx.x * 128 + wr * 64;
    const int bn = blockIdx.y * 128 + wc * 64;
    const int lrow = lane & 15;
    const int kgrp = (lane >> 4) * 8;

    f32x4 acc[4][4] = {};

    #pragma unroll
    for (int pass = 0; pass <= TWO; ++pass) {
        const unsigned short* Ap = pass ? A2 : A;
        const unsigned short* Bp = pass ? B2t : Bt;
        #pragma unroll 2
        for (int k0 = 0; k0 < DH; k0 += 32) {
            bf16x8 a[4], b[4];
            #pragma unroll
            for (int m = 0; m < 4; ++m)
                a[m] = *(const bf16x8*)(Ap + (size_t)(bm + m * 16 + lrow) * DH + k0 + kgrp);
            #pragma unroll
            for (int n = 0; n < 4; ++n)
                b[n] = *(const bf16x8*)(Bp + (size_t)(bn + n * 16 + lrow) * DH + k0 + kgrp);
            #pragma unroll
            for (int m = 0; m < 4; ++m)
                #pragma unroll
                for (int n = 0; n < 4; ++n)
                    acc[m][n] = __builtin_amdgcn_mfma_f32_16x16x32_bf16(a[m], b[n], acc[m][n], 0, 0, 0);
        }
    }

    const int crow0 = (lane >> 4) * 4;
    #pragma unroll
    for (int m = 0; m < 4; ++m) {
        #pragma unroll
        for (int r = 0; r < 4; ++r) {
            int row = bm + m * 16 + crow0 + r;
            if (row >= M) continue;
            #pragma unroll
            for (int n = 0; n < 4; ++n) {
                int col = bn + n * 16 + lrow;
                size_t idx = (size_t)row * DH + col;
                float v = acc[m][n][r];
                if (EPI) {
                    v += bias[col];
                    v = fmaxf(v, 0.f);
                    v += resid[idx];
                    Cf[idx] = v;
                }
                Cb[idx] = f2bf(v);
            }
        }
    }
}

// ------------------------------------------------------------------ launch
extern "C" void kernel_launch(void* const* d_in, const int* in_sizes, int n_in,
                              void* d_out, int out_size, void* d_ws, size_t ws_size,
                              hipStream_t stream) {
    const float* x    = (const float*)d_in[0];
    const int*   ei   = (const int*)d_in[1];
    const float* ea   = (const float*)d_in[2];
    const float* W0   = (const float*)d_in[3];
    const float* b0   = (const float*)d_in[4];
    const float* W1   = (const float*)d_in[5];
    const float* b1   = (const float*)d_in[6];
    const float* Wg   = (const float*)d_in[7];
    const float* bg   = (const float*)d_in[8];
    const float* a_src= (const float*)d_in[9];
    const float* a_dst= (const float*)d_in[10];
    const float* We   = (const float*)d_in[11];
    const float* a_e  = (const float*)d_in[12];
    const float* Ws   = (const float*)d_in[13];
    const float* Wn   = (const float*)d_in[14];
    const float* bm   = (const float*)d_in[15];
    float* out = (float*)d_out;

    const int N = in_sizes[0] / 3;
    const int E = in_sizes[1] / 2;
    const int Mpad = (N + 127) & ~127;
    const int* srcI = ei;
    const int* dstI = ei + E;

    char* p = (char*)d_ws;
    auto alloc = [&](size_t bytes) {
        void* r = (void*)p;
        p += (bytes + 255) & ~(size_t)255;
        return r;
    };
    size_t NF = (size_t)Mpad * DH * sizeof(float);
    size_t NBh = (size_t)Mpad * DH * sizeof(unsigned short);
    float* Hf0 = (float*)alloc(NF);
    float* Hf1 = (float*)alloc(NF);
    unsigned short* hbf  = (unsigned short*)alloc(NBh);
    unsigned short* hgbf = (unsigned short*)alloc(NBh);   // also reused as mean
    unsigned short* h1bf = (unsigned short*)alloc(NBh);
    unsigned short* Wt   = (unsigned short*)alloc((size_t)15 * DH * DH * sizeof(unsigned short));
    float* elog  = (float*)alloc((size_t)NLAYERS * E * sizeof(float));
    float* logit = (float*)alloc((size_t)E * sizeof(float));
    float* alpha = (float*)alloc((size_t)E * sizeof(float));
    int*   csrc  = (int*)alloc((size_t)E * sizeof(int));
    int*   ceid  = (int*)alloc((size_t)E * sizeof(int));
    int*   off   = (int*)alloc((size_t)(N + 1) * sizeof(int));
    int*   cnt   = (int*)alloc((size_t)N * sizeof(int));
    int*   cur   = (int*)alloc((size_t)N * sizeof(int));
    float* invd  = (float*)alloc((size_t)N * sizeof(float));
    float* ssrc  = (float*)alloc((size_t)N * sizeof(float));
    float* sdst  = (float*)alloc((size_t)N * sizeof(float));
    float* weae  = (float*)alloc((size_t)NLAYERS * DE * sizeof(float));

    const int EB = (E + 255) / 256;
    const int NB4 = (N + 3) / 4;
    const int MB = Mpad / 128;

    // ---- CSR build
    hipMemsetAsync(cnt, 0, (size_t)N * sizeof(int), stream);
    hipMemsetAsync(cur, 0, (size_t)N * sizeof(int), stream);
    k_count<<<EB, 256, 0, stream>>>(dstI, cnt, E);
    k_scan<<<1, 1024, 0, stream>>>(cnt, off, invd, N, E);
    k_fill<<<EB, 256, 0, stream>>>(srcI, dstI, off, cur, csrc, ceid, E);

    // ---- h-independent edge terms, weight transposes
    k_we_ae<<<1, 256, 0, stream>>>(We, a_e, weae);
    k_elogit<<<EB, 256, 0, stream>>>(ea, weae, elog, E);
    k_wt<<<dim3(8, 8, 15), dim3(32, 8), 0, stream>>>(Wg, Ws, Wn, Wt);

    // ---- input projection
    k_lin0<<<N, DH, 0, stream>>>(x, W0, b0, Hf0, hbf, N);

    // ---- residual blocks
    float* Hcur = Hf0;
    float* Hnxt = Hf1;
    for (int l = 0; l < NLAYERS; ++l) {
        const unsigned short* Wgt = Wt + (size_t)l * DH * DH;
        const unsigned short* Wst = Wt + (size_t)(5 + l) * DH * DH;
        const unsigned short* Wnt = Wt + (size_t)(10 + l) * DH * DH;
        unsigned short* meanbf = hgbf;  // hg dead after k_agg

        // hg = h @ Wg  (bf16 out only)
        k_gemm_mfma<0, 0><<<dim3(MB, 2), 256, 0, stream>>>(
            hbf, Wgt, nullptr, nullptr, nullptr, nullptr, nullptr, hgbf, N);
        k_dots<<<NB4, 256, 0, stream>>>(hgbf, a_src + (size_t)l * DH, a_dst + (size_t)l * DH,
                                        ssrc, sdst, N);
        k_logit<<<EB, 256, 0, stream>>>(ssrc, sdst, srcI, dstI, elog + (size_t)l * E, logit, E);
        k_softmax<<<NB4, 256, 0, stream>>>(off, ceid, logit, alpha, N);
        k_agg<<<NB4, 256, 0, stream>>>(off, csrc, alpha, hgbf, bg + (size_t)l * DH, h1bf, N);
        k_mean<<<NB4, 256, 0, stream>>>(off, csrc, h1bf, invd, meanbf, N);
        // Hnxt = relu(h1@Ws + mean@Wn + bm) + Hcur ; also write bf16 into hbf
        k_gemm_mfma<1, 1><<<dim3(MB, 2), 256, 0, stream>>>(
            h1bf, Wst, meanbf, Wnt, bm + (size_t)l * DH, Hcur, Hnxt, hbf, N);

        float* tmp = Hcur; Hcur = Hnxt; Hnxt = tmp;
    }

    // ---- output projection
    k_out<<<NB4, 256, 0, stream>>>(Hcur, W1, b1, out, N);
}

// Round 4
// 1913.617 us; speedup vs baseline: 2.0993x; 1.0892x over previous
//
#include <hip/hip_runtime.h>
#include <hip/hip_bf16.h>

#define DH 256
#define DE 32
#define NLAYERS 5
#define NEG_SLOPE 0.2f
#define EPSV 1e-16f
#define SEG 512

typedef __attribute__((ext_vector_type(8))) short bf16x8;
typedef __attribute__((ext_vector_type(4))) float f32x4;

__device__ inline float bf2f(unsigned short u) {
    unsigned x = ((unsigned)u) << 16;
    union { unsigned u; float f; } c; c.u = x; return c.f;
}
__device__ inline unsigned short f2bf(float f) {
    union { float f; unsigned u; } c; c.f = f;
    unsigned b = c.u;
    unsigned r = (b + 0x7FFF + ((b >> 16) & 1)) >> 16;
    return (unsigned short)r;
}

// ---------------------------------------------------------------- CSR build
__global__ void k_count(const int* __restrict__ dst, int* __restrict__ cnt, int E) {
    int e = blockIdx.x * 256 + threadIdx.x;
    if (e < E) atomicAdd(&cnt[dst[e]], 1);
}

// per-segment partial sums (coalesced)
__global__ void k_part(const int* __restrict__ cnt, int* __restrict__ part, int n) {
    int b = blockIdx.x, t = threadIdx.x;  // 512 threads
    int i = b * SEG + t;
    int v = (i < n) ? cnt[i] : 0;
    for (int d = 32; d; d >>= 1) v += __shfl_down(v, d);
    __shared__ int ws[8];
    int lane = t & 63, w = t >> 6;
    if (lane == 0) ws[w] = v;
    __syncthreads();
    if (t == 0) {
        int s = 0;
        #pragma unroll
        for (int k = 0; k < 8; ++k) s += ws[k];
        part[b] = s;
    }
}

// scan of <=128 partials (1 block, 128 threads)
__global__ void k_scanp(const int* __restrict__ part, int* __restrict__ base,
                        int* __restrict__ off, int nblk, int n, int total) {
    int t = threadIdx.x;
    int lane = t & 63, w = t >> 6;
    __shared__ int wsum[2];
    int v = (t < nblk) ? part[t] : 0;
    int incl = v;
    for (int d = 1; d < 64; d <<= 1) {
        int u = __shfl_up(incl, d);
        if (lane >= d) incl += u;
    }
    if (lane == 63) wsum[w] = incl;
    __syncthreads();
    int add = (w == 1) ? wsum[0] : 0;
    if (t < nblk) base[t] = incl - v + add;
    if (t == 0) off[n] = total;
}

// per-segment local exclusive scan + base -> off, invd
__global__ void k_emit(const int* __restrict__ cnt, const int* __restrict__ base,
                       int* __restrict__ off, float* __restrict__ invd, int n) {
    int b = blockIdx.x, t = threadIdx.x;  // 512 threads
    int i = b * SEG + t;
    int c = (i < n) ? cnt[i] : 0;
    int lane = t & 63, w = t >> 6;
    int incl = c;
    for (int d = 1; d < 64; d <<= 1) {
        int u = __shfl_up(incl, d);
        if (lane >= d) incl += u;
    }
    __shared__ int ws[8];
    if (lane == 63) ws[w] = incl;
    __syncthreads();
    int add = 0;
    for (int k = 0; k < w; ++k) add += ws[k];
    if (i < n) {
        off[i] = base[b] + add + incl - c;
        invd[i] = 1.0f / (float)max(c, 1);
    }
}

__global__ void k_fill(const int* __restrict__ src, const int* __restrict__ dst,
                       const int* __restrict__ off, int* __restrict__ cur,
                       int* __restrict__ csrc, int* __restrict__ pos, int E) {
    int e = blockIdx.x * 256 + threadIdx.x;
    if (e >= E) return;
    int d = dst[e];
    int p = off[d] + atomicAdd(&cur[d], 1);
    csrc[p] = src[e];
    pos[e] = p;
}

// ---------------------------------------------------------------- edge precompute
__global__ void k_we_ae(const float* __restrict__ We, const float* __restrict__ a_e,
                        float* __restrict__ out) {
    int t = threadIdx.x;
    if (t >= NLAYERS * DE) return;
    int l = t >> 5, d = t & 31;
    const float* w = We + ((size_t)l * DE + d) * DH;
    const float* ae = a_e + (size_t)l * DH;
    float s = 0.f;
    for (int j = 0; j < DH; ++j) s += w[j] * ae[j];
    out[t] = s;
}

// elogp[l][pos[e]] = edge_attr[e,:] . we_ae[l,:]  (scatter into CSR order)
__global__ void k_elogit(const float* __restrict__ ea, const float* __restrict__ we_ae,
                         const int* __restrict__ pos, float* __restrict__ elogp, int E) {
    __shared__ float w[NLAYERS * DE];
    if (threadIdx.x < NLAYERS * DE) w[threadIdx.x] = we_ae[threadIdx.x];
    __syncthreads();
    int e = blockIdx.x * 256 + threadIdx.x;
    if (e >= E) return;
    const float4* p = (const float4*)(ea + (size_t)e * DE);
    float r[NLAYERS] = {0, 0, 0, 0, 0};
    #pragma unroll
    for (int i = 0; i < DE / 4; ++i) {
        float4 x = p[i];
        #pragma unroll
        for (int l = 0; l < NLAYERS; ++l) {
            r[l] += x.x * w[l * DE + i * 4 + 0] + x.y * w[l * DE + i * 4 + 1] +
                    x.z * w[l * DE + i * 4 + 2] + x.w * w[l * DE + i * 4 + 3];
        }
    }
    int q = pos[e];
    #pragma unroll
    for (int l = 0; l < NLAYERS; ++l) elogp[(size_t)l * E + q] = r[l];
}

// ---------------------------------------------------------------- weight transpose fp32 -> bf16
__global__ void k_wt(const float* __restrict__ Wg, const float* __restrict__ Ws,
                     const float* __restrict__ Wn, unsigned short* __restrict__ Wt) {
    __shared__ float tile[32][33];
    int z = blockIdx.z;
    const float* W = z < 5 ? Wg + (size_t)z * DH * DH
                   : (z < 10 ? Ws + (size_t)(z - 5) * DH * DH
                             : Wn + (size_t)(z - 10) * DH * DH);
    unsigned short* out = Wt + (size_t)z * DH * DH;
    int c0 = blockIdx.x * 32, r0 = blockIdx.y * 32;
    int tx = threadIdx.x, ty = threadIdx.y;
    for (int j = ty; j < 32; j += 8) tile[j][tx] = W[(size_t)(r0 + j) * DH + c0 + tx];
    __syncthreads();
    for (int j = ty; j < 32; j += 8)
        out[(size_t)(c0 + j) * DH + r0 + tx] = f2bf(tile[tx][j]);
}

// ---------------------------------------------------------------- lin0 (bf16 out)
__global__ void k_lin0(const float* __restrict__ x, const float* __restrict__ W0,
                       const float* __restrict__ b0, unsigned short* __restrict__ hb, int n) {
    int node = blockIdx.x;
    int c = threadIdx.x;
    if (node >= n) return;
    float x0 = x[(size_t)node * 3 + 0];
    float x1 = x[(size_t)node * 3 + 1];
    float x2 = x[(size_t)node * 3 + 2];
    float v = b0[c] + x0 * W0[c] + x1 * W0[DH + c] + x2 * W0[2 * DH + c];
    hb[(size_t)node * DH + c] = f2bf(v);
}

// ---------------------------------------------------------------- per-node dots
__global__ void k_dots(const unsigned short* __restrict__ hg, const float* __restrict__ asrc,
                       const float* __restrict__ adst, float* __restrict__ ssrc,
                       float* __restrict__ sdst, int n) {
    int wave = threadIdx.x >> 6, lane = threadIdx.x & 63;
    int row = blockIdx.x * 4 + wave;
    if (row >= n) return;
    ushort4 v = *(const ushort4*)(hg + (size_t)row * DH + lane * 4);
    float4 wa = *(const float4*)(asrc + lane * 4);
    float4 wb = *(const float4*)(adst + lane * 4);
    float f0 = bf2f(v.x), f1 = bf2f(v.y), f2 = bf2f(v.z), f3 = bf2f(v.w);
    float a = f0 * wa.x + f1 * wa.y + f2 * wa.z + f3 * wa.w;
    float b = f0 * wb.x + f1 * wb.y + f2 * wb.z + f3 * wb.w;
    for (int d = 32; d; d >>= 1) { a += __shfl_down(a, d); b += __shfl_down(b, d); }
    if (lane == 0) { ssrc[row] = a; sdst[row] = b; }
}

// ---------------------------------------------------------------- fused logit + segment softmax
__global__ void k_softmax(const int* __restrict__ off, const int* __restrict__ csrc,
                          const float* __restrict__ ssrc, const float* __restrict__ sdst,
                          const float* __restrict__ elogp, float* __restrict__ logitp,
                          float* __restrict__ alpha, int n) {
    int wave = threadIdx.x >> 6, lane = threadIdx.x & 63;
    int node = blockIdx.x * 4 + wave;
    if (node >= n) return;
    int p0 = off[node], p1 = off[node + 1];
    float sd = sdst[node];
    float m = -3.4e38f;
    for (int p = p0 + lane; p < p1; p += 64) {
        float raw = ssrc[csrc[p]] + sd + elogp[p];
        raw = raw > 0.f ? raw : NEG_SLOPE * raw;
        logitp[p] = raw;
        m = fmaxf(m, raw);
    }
    for (int d = 32; d; d >>= 1) m = fmaxf(m, __shfl_xor(m, d));
    float s = 0.f;
    for (int p = p0 + lane; p < p1; p += 64) s += expf(logitp[p] - m);
    for (int d = 32; d; d >>= 1) s += __shfl_xor(s, d);
    float inv = 1.0f / (s + EPSV);
    for (int p = p0 + lane; p < p1; p += 64) alpha[p] = expf(logitp[p] - m) * inv;
}

// ---------------------------------------------------------------- GAT aggregate
__global__ void k_agg(const int* __restrict__ off, const int* __restrict__ csrc,
                      const float* __restrict__ alpha, const unsigned short* __restrict__ hg,
                      const float* __restrict__ bias, unsigned short* __restrict__ h1, int n) {
    int wave = threadIdx.x >> 6, lane = threadIdx.x & 63;
    int node = blockIdx.x * 4 + wave;
    if (node >= n) return;
    int p0 = off[node], p1 = off[node + 1];
    int c = lane * 4;
    float a0 = 0.f, a1 = 0.f, a2 = 0.f, a3 = 0.f;
    for (int p = p0; p < p1; ++p) {
        float a = alpha[p];
        ushort4 v = *(const ushort4*)(hg + (size_t)csrc[p] * DH + c);
        a0 += a * bf2f(v.x); a1 += a * bf2f(v.y);
        a2 += a * bf2f(v.z); a3 += a * bf2f(v.w);
    }
    float4 bb = *(const float4*)(bias + c);
    ushort4 o;
    o.x = f2bf(fmaxf(a0 + bb.x, 0.f));
    o.y = f2bf(fmaxf(a1 + bb.y, 0.f));
    o.z = f2bf(fmaxf(a2 + bb.z, 0.f));
    o.w = f2bf(fmaxf(a3 + bb.w, 0.f));
    *(ushort4*)(h1 + (size_t)node * DH + c) = o;
}

// ---------------------------------------------------------------- mean aggregate
__global__ void k_mean(const int* __restrict__ off, const int* __restrict__ csrc,
                       const unsigned short* __restrict__ h1, const float* __restrict__ inv_deg,
                       unsigned short* __restrict__ mean, int n) {
    int wave = threadIdx.x >> 6, lane = threadIdx.x & 63;
    int node = blockIdx.x * 4 + wave;
    if (node >= n) return;
    int p0 = off[node], p1 = off[node + 1];
    int c = lane * 4;
    float a0 = 0.f, a1 = 0.f, a2 = 0.f, a3 = 0.f;
    for (int p = p0; p < p1; ++p) {
        ushort4 v = *(const ushort4*)(h1 + (size_t)csrc[p] * DH + c);
        a0 += bf2f(v.x); a1 += bf2f(v.y); a2 += bf2f(v.z); a3 += bf2f(v.w);
    }
    float inv = inv_deg[node];
    ushort4 o;
    o.x = f2bf(a0 * inv); o.y = f2bf(a1 * inv);
    o.z = f2bf(a2 * inv); o.w = f2bf(a3 * inv);
    *(ushort4*)(mean + (size_t)node * DH + c) = o;
}

// ---------------------------------------------------------------- final projection (bf16 H)
__global__ void k_out(const unsigned short* __restrict__ h, const float* __restrict__ W1,
                      const float* __restrict__ b1, float* __restrict__ out, int n) {
    int wave = threadIdx.x >> 6, lane = threadIdx.x & 63;
    int row = blockIdx.x * 4 + wave;
    if (row >= n) return;
    ushort4 v = *(const ushort4*)(h + (size_t)row * DH + lane * 4);
    float4 w1 = *(const float4*)(W1 + lane * 4);
    float s = bf2f(v.x) * w1.x + bf2f(v.y) * w1.y + bf2f(v.z) * w1.z + bf2f(v.w) * w1.w;
    for (int d = 32; d; d >>= 1) s += __shfl_down(s, d);
    if (lane == 0) out[row] = s + b1[0];
}

// ---------------------------------------------------------------- MFMA GEMM
// C[M,256] = (A@B) [+ A2@B2]; EPI: +bias, relu, + bf16 resid. All storage bf16.
template <int TWO, int EPI>
__global__ __launch_bounds__(256) void k_gemm_mfma(
    const unsigned short* __restrict__ A, const unsigned short* __restrict__ Bt,
    const unsigned short* __restrict__ A2, const unsigned short* __restrict__ B2t,
    const float* __restrict__ bias, const unsigned short* __restrict__ resid,
    unsigned short* __restrict__ Cb, int M) {
    const int t = threadIdx.x;
    const int wid = t >> 6, lane = t & 63;
    const int wr = wid >> 1, wc = wid & 1;
    const int bm = blockIdx.x * 128 + wr * 64;
    const int bn = blockIdx.y * 128 + wc * 64;
    const int lrow = lane & 15;
    const int kgrp = (lane >> 4) * 8;

    f32x4 acc[4][4] = {};

    #pragma unroll
    for (int pass = 0; pass <= TWO; ++pass) {
        const unsigned short* Ap = pass ? A2 : A;
        const unsigned short* Bp = pass ? B2t : Bt;
        #pragma unroll 2
        for (int k0 = 0; k0 < DH; k0 += 32) {
            bf16x8 a[4], b[4];
            #pragma unroll
            for (int m = 0; m < 4; ++m)
                a[m] = *(const bf16x8*)(Ap + (size_t)(bm + m * 16 + lrow) * DH + k0 + kgrp);
            #pragma unroll
            for (int n = 0; n < 4; ++n)
                b[n] = *(const bf16x8*)(Bp + (size_t)(bn + n * 16 + lrow) * DH + k0 + kgrp);
            #pragma unroll
            for (int m = 0; m < 4; ++m)
                #pragma unroll
                for (int n = 0; n < 4; ++n)
                    acc[m][n] = __builtin_amdgcn_mfma_f32_16x16x32_bf16(a[m], b[n], acc[m][n], 0, 0, 0);
        }
    }

    const int crow0 = (lane >> 4) * 4;
    #pragma unroll
    for (int m = 0; m < 4; ++m) {
        #pragma unroll
        for (int r = 0; r < 4; ++r) {
            int row = bm + m * 16 + crow0 + r;
            if (row >= M) continue;
            #pragma unroll
            for (int n = 0; n < 4; ++n) {
                int col = bn + n * 16 + lrow;
                size_t idx = (size_t)row * DH + col;
                float v = acc[m][n][r];
                if (EPI) {
                    v += bias[col];
                    v = fmaxf(v, 0.f);
                    v += bf2f(resid[idx]);
                }
                Cb[idx] = f2bf(v);
            }
        }
    }
}

// ------------------------------------------------------------------ launch
extern "C" void kernel_launch(void* const* d_in, const int* in_sizes, int n_in,
                              void* d_out, int out_size, void* d_ws, size_t ws_size,
                              hipStream_t stream) {
    const float* x    = (const float*)d_in[0];
    const int*   ei   = (const int*)d_in[1];
    const float* ea   = (const float*)d_in[2];
    const float* W0   = (const float*)d_in[3];
    const float* b0   = (const float*)d_in[4];
    const float* W1   = (const float*)d_in[5];
    const float* b1   = (const float*)d_in[6];
    const float* Wg   = (const float*)d_in[7];
    const float* bg   = (const float*)d_in[8];
    const float* a_src= (const float*)d_in[9];
    const float* a_dst= (const float*)d_in[10];
    const float* We   = (const float*)d_in[11];
    const float* a_e  = (const float*)d_in[12];
    const float* Ws   = (const float*)d_in[13];
    const float* Wn   = (const float*)d_in[14];
    const float* bm   = (const float*)d_in[15];
    float* out = (float*)d_out;

    const int N = in_sizes[0] / 3;
    const int E = in_sizes[1] / 2;
    const int Mpad = (N + 127) & ~127;
    const int* srcI = ei;
    const int* dstI = ei + E;

    char* p = (char*)d_ws;
    auto alloc = [&](size_t bytes) {
        void* r = (void*)p;
        p += (bytes + 255) & ~(size_t)255;
        return r;
    };
    size_t NBh = (size_t)Mpad * DH * sizeof(unsigned short);
    unsigned short* Hb0  = (unsigned short*)alloc(NBh);
    unsigned short* Hb1  = (unsigned short*)alloc(NBh);
    unsigned short* hgbf = (unsigned short*)alloc(NBh);   // reused as mean
    unsigned short* h1bf = (unsigned short*)alloc(NBh);
    unsigned short* Wt   = (unsigned short*)alloc((size_t)15 * DH * DH * sizeof(unsigned short));
    float* elogp = (float*)alloc((size_t)NLAYERS * E * sizeof(float));
    float* logitp= (float*)alloc((size_t)E * sizeof(float));
    float* alpha = (float*)alloc((size_t)E * sizeof(float));
    int*   csrc  = (int*)alloc((size_t)E * sizeof(int));
    int*   pos   = (int*)alloc((size_t)E * sizeof(int));
    int*   off   = (int*)alloc((size_t)(N + 1) * sizeof(int));
    int*   cnt   = (int*)alloc((size_t)N * sizeof(int));
    int*   cur   = (int*)alloc((size_t)N * sizeof(int));
    float* invd  = (float*)alloc((size_t)N * sizeof(float));
    float* ssrc  = (float*)alloc((size_t)N * sizeof(float));
    float* sdst  = (float*)alloc((size_t)N * sizeof(float));
    float* weae  = (float*)alloc((size_t)NLAYERS * DE * sizeof(float));
    const int NBLK = (N + SEG - 1) / SEG;  // 98 for N=50000 (must be <=128)
    int* part = (int*)alloc((size_t)NBLK * sizeof(int));
    int* base = (int*)alloc((size_t)NBLK * sizeof(int));

    const int EB = (E + 255) / 256;
    const int NB4 = (N + 3) / 4;
    const int MB = Mpad / 128;

    // ---- CSR build
    hipMemsetAsync(cnt, 0, (size_t)N * sizeof(int), stream);
    hipMemsetAsync(cur, 0, (size_t)N * sizeof(int), stream);
    k_count<<<EB, 256, 0, stream>>>(dstI, cnt, E);
    k_part<<<NBLK, SEG, 0, stream>>>(cnt, part, N);
    k_scanp<<<1, 128, 0, stream>>>(part, base, off, NBLK, N, E);
    k_emit<<<NBLK, SEG, 0, stream>>>(cnt, base, off, invd, N);
    k_fill<<<EB, 256, 0, stream>>>(srcI, dstI, off, cur, csrc, pos, E);

    // ---- h-independent edge terms (CSR-ordered), weight transposes
    k_we_ae<<<1, 256, 0, stream>>>(We, a_e, weae);
    k_elogit<<<EB, 256, 0, stream>>>(ea, weae, pos, elogp, E);
    k_wt<<<dim3(8, 8, 15), dim3(32, 8), 0, stream>>>(Wg, Ws, Wn, Wt);

    // ---- input projection
    k_lin0<<<N, DH, 0, stream>>>(x, W0, b0, Hb0, N);

    // ---- residual blocks
    unsigned short* Hcur = Hb0;
    unsigned short* Hnxt = Hb1;
    for (int l = 0; l < NLAYERS; ++l) {
        const unsigned short* Wgt = Wt + (size_t)l * DH * DH;
        const unsigned short* Wst = Wt + (size_t)(5 + l) * DH * DH;
        const unsigned short* Wnt = Wt + (size_t)(10 + l) * DH * DH;
        unsigned short* meanbf = hgbf;  // hg dead after k_agg

        k_gemm_mfma<0, 0><<<dim3(MB, 2), 256, 0, stream>>>(
            Hcur, Wgt, nullptr, nullptr, nullptr, nullptr, hgbf, N);
        k_dots<<<NB4, 256, 0, stream>>>(hgbf, a_src + (size_t)l * DH, a_dst + (size_t)l * DH,
                                        ssrc, sdst, N);
        k_softmax<<<NB4, 256, 0, stream>>>(off, csrc, ssrc, sdst,
                                           elogp + (size_t)l * E, logitp, alpha, N);
        k_agg<<<NB4, 256, 0, stream>>>(off, csrc, alpha, hgbf, bg + (size_t)l * DH, h1bf, N);
        k_mean<<<NB4, 256, 0, stream>>>(off, csrc, h1bf, invd, meanbf, N);
        k_gemm_mfma<1, 1><<<dim3(MB, 2), 256, 0, stream>>>(
            h1bf, Wst, meanbf, Wnt, bm + (size_t)l * DH, Hcur, Hnxt, N);

        unsigned short* tmp = Hcur; Hcur = Hnxt; Hnxt = tmp;
    }

    // ---- output projection
    k_out<<<NB4, 256, 0, stream>>>(Hcur, W1, b1, out, N);
}

// Round 5
// 1528.401 us; speedup vs baseline: 2.6284x; 1.2520x over previous
//
#include <hip/hip_runtime.h>
#include <hip/hip_bf16.h>

#define DH 256
#define DE 32
#define NLAYERS 5
#define NEG_SLOPE 0.2f
#define EPSV 1e-16f
#define SEG 512

typedef __attribute__((ext_vector_type(8))) short bf16x8;
typedef __attribute__((ext_vector_type(4))) float f32x4;

__device__ inline float bf2f(unsigned short u) {
    unsigned x = ((unsigned)u) << 16;
    union { unsigned u; float f; } c; c.u = x; return c.f;
}
__device__ inline unsigned short f2bf(float f) {
    union { float f; unsigned u; } c; c.f = f;
    unsigned b = c.u;
    unsigned r = (b + 0x7FFF + ((b >> 16) & 1)) >> 16;
    return (unsigned short)r;
}

// ---------------------------------------------------------------- CSR build
__global__ void k_count(const int* __restrict__ dst, int* __restrict__ cnt, int E) {
    int e = blockIdx.x * 256 + threadIdx.x;
    if (e < E) atomicAdd(&cnt[dst[e]], 1);
}

__global__ void k_part(const int* __restrict__ cnt, int* __restrict__ part, int n) {
    int b = blockIdx.x, t = threadIdx.x;  // 512 threads
    int i = b * SEG + t;
    int v = (i < n) ? cnt[i] : 0;
    for (int d = 32; d; d >>= 1) v += __shfl_down(v, d);
    __shared__ int ws[8];
    int lane = t & 63, w = t >> 6;
    if (lane == 0) ws[w] = v;
    __syncthreads();
    if (t == 0) {
        int s = 0;
        #pragma unroll
        for (int k = 0; k < 8; ++k) s += ws[k];
        part[b] = s;
    }
}

__global__ void k_scanp(const int* __restrict__ part, int* __restrict__ base,
                        int* __restrict__ off, int nblk, int n, int total) {
    int t = threadIdx.x;
    int lane = t & 63, w = t >> 6;
    __shared__ int wsum[2];
    int v = (t < nblk) ? part[t] : 0;
    int incl = v;
    for (int d = 1; d < 64; d <<= 1) {
        int u = __shfl_up(incl, d);
        if (lane >= d) incl += u;
    }
    if (lane == 63) wsum[w] = incl;
    __syncthreads();
    int add = (w == 1) ? wsum[0] : 0;
    if (t < nblk) base[t] = incl - v + add;
    if (t == 0) off[n] = total;
}

__global__ void k_emit(const int* __restrict__ cnt, const int* __restrict__ base,
                       int* __restrict__ off, float* __restrict__ invd, int n) {
    int b = blockIdx.x, t = threadIdx.x;  // 512 threads
    int i = b * SEG + t;
    int c = (i < n) ? cnt[i] : 0;
    int lane = t & 63, w = t >> 6;
    int incl = c;
    for (int d = 1; d < 64; d <<= 1) {
        int u = __shfl_up(incl, d);
        if (lane >= d) incl += u;
    }
    __shared__ int ws[8];
    if (lane == 63) ws[w] = incl;
    __syncthreads();
    int add = 0;
    for (int k = 0; k < w; ++k) add += ws[k];
    if (i < n) {
        off[i] = base[b] + add + incl - c;
        invd[i] = 1.0f / (float)max(c, 1);
    }
}

__global__ void k_fill(const int* __restrict__ src, const int* __restrict__ dst,
                       const int* __restrict__ off, int* __restrict__ cur,
                       int* __restrict__ csrc, int* __restrict__ pos, int E) {
    int e = blockIdx.x * 256 + threadIdx.x;
    if (e >= E) return;
    int d = dst[e];
    int p = off[d] + atomicAdd(&cur[d], 1);
    csrc[p] = src[e];
    pos[e] = p;
}

// ---------------------------------------------------------------- edge precompute
__global__ void k_we_ae(const float* __restrict__ We, const float* __restrict__ a_e,
                        float* __restrict__ out) {
    int t = threadIdx.x;
    if (t >= NLAYERS * DE) return;
    int l = t >> 5, d = t & 31;
    const float* w = We + ((size_t)l * DE + d) * DH;
    const float* ae = a_e + (size_t)l * DH;
    float s = 0.f;
    for (int j = 0; j < DH; ++j) s += w[j] * ae[j];
    out[t] = s;
}

__global__ void k_elogit(const float* __restrict__ ea, const float* __restrict__ we_ae,
                         const int* __restrict__ pos, float* __restrict__ elogp, int E) {
    __shared__ float w[NLAYERS * DE];
    if (threadIdx.x < NLAYERS * DE) w[threadIdx.x] = we_ae[threadIdx.x];
    __syncthreads();
    int e = blockIdx.x * 256 + threadIdx.x;
    if (e >= E) return;
    const float4* p = (const float4*)(ea + (size_t)e * DE);
    float r[NLAYERS] = {0, 0, 0, 0, 0};
    #pragma unroll
    for (int i = 0; i < DE / 4; ++i) {
        float4 x = p[i];
        #pragma unroll
        for (int l = 0; l < NLAYERS; ++l) {
            r[l] += x.x * w[l * DE + i * 4 + 0] + x.y * w[l * DE + i * 4 + 1] +
                    x.z * w[l * DE + i * 4 + 2] + x.w * w[l * DE + i * 4 + 3];
        }
    }
    int q = pos[e];
    #pragma unroll
    for (int l = 0; l < NLAYERS; ++l) elogp[(size_t)l * E + q] = r[l];
}

// ---------------------------------------------------------------- weight transpose fp32 -> bf16
__global__ void k_wt(const float* __restrict__ Wg, const float* __restrict__ Ws,
                     const float* __restrict__ Wn, unsigned short* __restrict__ Wt) {
    __shared__ float tile[32][33];
    int z = blockIdx.z;
    const float* W = z < 5 ? Wg + (size_t)z * DH * DH
                   : (z < 10 ? Ws + (size_t)(z - 5) * DH * DH
                             : Wn + (size_t)(z - 10) * DH * DH);
    unsigned short* out = Wt + (size_t)z * DH * DH;
    int c0 = blockIdx.x * 32, r0 = blockIdx.y * 32;
    int tx = threadIdx.x, ty = threadIdx.y;
    for (int j = ty; j < 32; j += 8) tile[j][tx] = W[(size_t)(r0 + j) * DH + c0 + tx];
    __syncthreads();
    for (int j = ty; j < 32; j += 8)
        out[(size_t)(c0 + j) * DH + r0 + tx] = f2bf(tile[tx][j]);
}

// ---------------------------------------------------------------- lin0 (bf16 out)
__global__ void k_lin0(const float* __restrict__ x, const float* __restrict__ W0,
                       const float* __restrict__ b0, unsigned short* __restrict__ hb, int n) {
    int node = blockIdx.x;
    int c = threadIdx.x;
    if (node >= n) return;
    float x0 = x[(size_t)node * 3 + 0];
    float x1 = x[(size_t)node * 3 + 1];
    float x2 = x[(size_t)node * 3 + 2];
    float v = b0[c] + x0 * W0[c] + x1 * W0[DH + c] + x2 * W0[2 * DH + c];
    hb[(size_t)node * DH + c] = f2bf(v);
}

// ---------------------------------------------------------------- per-node dots
__global__ void k_dots(const unsigned short* __restrict__ hg, const float* __restrict__ asrc,
                       const float* __restrict__ adst, float* __restrict__ ssrc,
                       float* __restrict__ sdst, int n) {
    int wave = threadIdx.x >> 6, lane = threadIdx.x & 63;
    int row = blockIdx.x * 4 + wave;
    if (row >= n) return;
    ushort4 v = *(const ushort4*)(hg + (size_t)row * DH + lane * 4);
    float4 wa = *(const float4*)(asrc + lane * 4);
    float4 wb = *(const float4*)(adst + lane * 4);
    float f0 = bf2f(v.x), f1 = bf2f(v.y), f2 = bf2f(v.z), f3 = bf2f(v.w);
    float a = f0 * wa.x + f1 * wa.y + f2 * wa.z + f3 * wa.w;
    float b = f0 * wb.x + f1 * wb.y + f2 * wb.z + f3 * wb.w;
    for (int d = 32; d; d >>= 1) { a += __shfl_down(a, d); b += __shfl_down(b, d); }
    if (lane == 0) { ssrc[row] = a; sdst[row] = b; }
}

// ---------------------------------------------------------------- fused logit+softmax+aggregate
// Wave per node. Edge exp-logits kept in 4 lane-owned scalar regs (deg<=256);
// alpha & src id broadcast via shfl. Gather unrolled x4 for memory-level parallelism.
__global__ void k_attn(const int* __restrict__ off, const int* __restrict__ csrc,
                       const float* __restrict__ ssrc, const float* __restrict__ sdst,
                       const float* __restrict__ elogp, const unsigned short* __restrict__ hg,
                       const float* __restrict__ bias, unsigned short* __restrict__ h1, int n) {
    int wave = threadIdx.x >> 6, lane = threadIdx.x & 63;
    int node = blockIdx.x * 4 + wave;
    if (node >= n) return;
    int p0 = off[node], p1 = off[node + 1];
    int deg = p1 - p0;
    float sd = sdst[node];
    int c = lane * 4;
    float a0 = 0.f, a1 = 0.f, a2 = 0.f, a3 = 0.f;

    if (deg <= 256) {
        float ex0 = 0.f, ex1 = 0.f, ex2 = 0.f, ex3 = 0.f;
        int cs0 = 0, cs1 = 0, cs2 = 0, cs3 = 0;
        float m = -3.4e38f;
        {
            int p = p0 + lane;
            if (p < p1) { cs0 = csrc[p]; float r = ssrc[cs0] + sd + elogp[p];
                          r = r > 0.f ? r : NEG_SLOPE * r; ex0 = r; m = fmaxf(m, r); }
            p += 64;
            if (p < p1) { cs1 = csrc[p]; float r = ssrc[cs1] + sd + elogp[p];
                          r = r > 0.f ? r : NEG_SLOPE * r; ex1 = r; m = fmaxf(m, r); }
            p += 64;
            if (p < p1) { cs2 = csrc[p]; float r = ssrc[cs2] + sd + elogp[p];
                          r = r > 0.f ? r : NEG_SLOPE * r; ex2 = r; m = fmaxf(m, r); }
            p += 64;
            if (p < p1) { cs3 = csrc[p]; float r = ssrc[cs3] + sd + elogp[p];
                          r = r > 0.f ? r : NEG_SLOPE * r; ex3 = r; m = fmaxf(m, r); }
        }
        for (int d = 32; d; d >>= 1) m = fmaxf(m, __shfl_xor(m, d));
        float den = 0.f;
        {
            int p = p0 + lane;
            if (p < p1) { ex0 = expf(ex0 - m); den += ex0; }
            p += 64;
            if (p < p1) { ex1 = expf(ex1 - m); den += ex1; }
            p += 64;
            if (p < p1) { ex2 = expf(ex2 - m); den += ex2; }
            p += 64;
            if (p < p1) { ex3 = expf(ex3 - m); den += ex3; }
        }
        for (int d = 32; d; d >>= 1) den += __shfl_xor(den, d);
        float inv = 1.0f / (den + EPSV);

        #define EDGEA(u, WV, SV) { int q = p + (u) - p0; int jj = q >> 6; int sl = q & 63; \
            float ev = ex0; if (jj == 1) ev = ex1; else if (jj == 2) ev = ex2; else if (jj == 3) ev = ex3; \
            int cv = cs0; if (jj == 1) cv = cs1; else if (jj == 2) cv = cs2; else if (jj == 3) cv = cs3; \
            WV = __shfl(ev, sl) * inv; SV = __shfl(cv, sl); }

        int p = p0;
        for (; p + 4 <= p1; p += 4) {
            float w0, w1, w2, w3; int s0, s1, s2, s3;
            EDGEA(0, w0, s0) EDGEA(1, w1, s1) EDGEA(2, w2, s2) EDGEA(3, w3, s3)
            ushort4 v0 = *(const ushort4*)(hg + (size_t)s0 * DH + c);
            ushort4 v1 = *(const ushort4*)(hg + (size_t)s1 * DH + c);
            ushort4 v2 = *(const ushort4*)(hg + (size_t)s2 * DH + c);
            ushort4 v3 = *(const ushort4*)(hg + (size_t)s3 * DH + c);
            a0 += w0 * bf2f(v0.x) + w1 * bf2f(v1.x) + w2 * bf2f(v2.x) + w3 * bf2f(v3.x);
            a1 += w0 * bf2f(v0.y) + w1 * bf2f(v1.y) + w2 * bf2f(v2.y) + w3 * bf2f(v3.y);
            a2 += w0 * bf2f(v0.z) + w1 * bf2f(v1.z) + w2 * bf2f(v2.z) + w3 * bf2f(v3.z);
            a3 += w0 * bf2f(v0.w) + w1 * bf2f(v1.w) + w2 * bf2f(v2.w) + w3 * bf2f(v3.w);
        }
        for (; p < p1; ++p) {
            float w0; int s0;
            EDGEA(0, w0, s0)
            ushort4 v0 = *(const ushort4*)(hg + (size_t)s0 * DH + c);
            a0 += w0 * bf2f(v0.x); a1 += w0 * bf2f(v0.y);
            a2 += w0 * bf2f(v0.z); a3 += w0 * bf2f(v0.w);
        }
        #undef EDGEA
    } else {
        // fallback: never expected at this degree distribution, correctness only
        float m = -3.4e38f;
        for (int p = p0 + lane; p < p1; p += 64) {
            float r = ssrc[csrc[p]] + sd + elogp[p];
            r = r > 0.f ? r : NEG_SLOPE * r;
            m = fmaxf(m, r);
        }
        for (int d = 32; d; d >>= 1) m = fmaxf(m, __shfl_xor(m, d));
        float den = 0.f;
        for (int p = p0 + lane; p < p1; p += 64) {
            float r = ssrc[csrc[p]] + sd + elogp[p];
            r = r > 0.f ? r : NEG_SLOPE * r;
            den += expf(r - m);
        }
        for (int d = 32; d; d >>= 1) den += __shfl_xor(den, d);
        float inv = 1.0f / (den + EPSV);
        for (int p = p0; p < p1; ++p) {
            int sn = csrc[p];
            float r = ssrc[sn] + sd + elogp[p];
            r = r > 0.f ? r : NEG_SLOPE * r;
            float a = expf(r - m) * inv;
            ushort4 v = *(const ushort4*)(hg + (size_t)sn * DH + c);
            a0 += a * bf2f(v.x); a1 += a * bf2f(v.y);
            a2 += a * bf2f(v.z); a3 += a * bf2f(v.w);
        }
    }

    float4 bb = *(const float4*)(bias + c);
    ushort4 o;
    o.x = f2bf(fmaxf(a0 + bb.x, 0.f));
    o.y = f2bf(fmaxf(a1 + bb.y, 0.f));
    o.z = f2bf(fmaxf(a2 + bb.z, 0.f));
    o.w = f2bf(fmaxf(a3 + bb.w, 0.f));
    *(ushort4*)(h1 + (size_t)node * DH + c) = o;
}

// ---------------------------------------------------------------- mean aggregate (x4 unroll)
__global__ void k_mean(const int* __restrict__ off, const int* __restrict__ csrc,
                       const unsigned short* __restrict__ h1, const float* __restrict__ inv_deg,
                       unsigned short* __restrict__ mean, int n) {
    int wave = threadIdx.x >> 6, lane = threadIdx.x & 63;
    int node = blockIdx.x * 4 + wave;
    if (node >= n) return;
    int p0 = off[node], p1 = off[node + 1];
    int c = lane * 4;
    float a0 = 0.f, a1 = 0.f, a2 = 0.f, a3 = 0.f;
    int p = p0;
    for (; p + 4 <= p1; p += 4) {
        int s0 = csrc[p], s1 = csrc[p + 1], s2 = csrc[p + 2], s3 = csrc[p + 3];
        ushort4 v0 = *(const ushort4*)(h1 + (size_t)s0 * DH + c);
        ushort4 v1 = *(const ushort4*)(h1 + (size_t)s1 * DH + c);
        ushort4 v2 = *(const ushort4*)(h1 + (size_t)s2 * DH + c);
        ushort4 v3 = *(const ushort4*)(h1 + (size_t)s3 * DH + c);
        a0 += bf2f(v0.x) + bf2f(v1.x) + bf2f(v2.x) + bf2f(v3.x);
        a1 += bf2f(v0.y) + bf2f(v1.y) + bf2f(v2.y) + bf2f(v3.y);
        a2 += bf2f(v0.z) + bf2f(v1.z) + bf2f(v2.z) + bf2f(v3.z);
        a3 += bf2f(v0.w) + bf2f(v1.w) + bf2f(v2.w) + bf2f(v3.w);
    }
    for (; p < p1; ++p) {
        ushort4 v = *(const ushort4*)(h1 + (size_t)csrc[p] * DH + c);
        a0 += bf2f(v.x); a1 += bf2f(v.y); a2 += bf2f(v.z); a3 += bf2f(v.w);
    }
    float inv = inv_deg[node];
    ushort4 o;
    o.x = f2bf(a0 * inv); o.y = f2bf(a1 * inv);
    o.z = f2bf(a2 * inv); o.w = f2bf(a3 * inv);
    *(ushort4*)(mean + (size_t)node * DH + c) = o;
}

// ---------------------------------------------------------------- final projection (bf16 H)
__global__ void k_out(const unsigned short* __restrict__ h, const float* __restrict__ W1,
                      const float* __restrict__ b1, float* __restrict__ out, int n) {
    int wave = threadIdx.x >> 6, lane = threadIdx.x & 63;
    int row = blockIdx.x * 4 + wave;
    if (row >= n) return;
    ushort4 v = *(const ushort4*)(h + (size_t)row * DH + lane * 4);
    float4 w1 = *(const float4*)(W1 + lane * 4);
    float s = bf2f(v.x) * w1.x + bf2f(v.y) * w1.y + bf2f(v.z) * w1.z + bf2f(v.w) * w1.w;
    for (int d = 32; d; d >>= 1) s += __shfl_down(s, d);
    if (lane == 0) out[row] = s + b1[0];
}

// ---------------------------------------------------------------- MFMA GEMM
template <int TWO, int EPI>
__global__ __launch_bounds__(256) void k_gemm_mfma(
    const unsigned short* __restrict__ A, const unsigned short* __restrict__ Bt,
    const unsigned short* __restrict__ A2, const unsigned short* __restrict__ B2t,
    const float* __restrict__ bias, const unsigned short* __restrict__ resid,
    unsigned short* __restrict__ Cb, int M) {
    const int t = threadIdx.x;
    const int wid = t >> 6, lane = t & 63;
    const int wr = wid >> 1, wc = wid & 1;
    const int bm = blockIdx.x * 128 + wr * 64;
    const int bn = blockIdx.y * 128 + wc * 64;
    const int lrow = lane & 15;
    const int kgrp = (lane >> 4) * 8;

    f32x4 acc[4][4] = {};

    #pragma unroll
    for (int pass = 0; pass <= TWO; ++pass) {
        const unsigned short* Ap = pass ? A2 : A;
        const unsigned short* Bp = pass ? B2t : Bt;
        #pragma unroll 2
        for (int k0 = 0; k0 < DH; k0 += 32) {
            bf16x8 a[4], b[4];
            #pragma unroll
            for (int m = 0; m < 4; ++m)
                a[m] = *(const bf16x8*)(Ap + (size_t)(bm + m * 16 + lrow) * DH + k0 + kgrp);
            #pragma unroll
            for (int n = 0; n < 4; ++n)
                b[n] = *(const bf16x8*)(Bp + (size_t)(bn + n * 16 + lrow) * DH + k0 + kgrp);
            #pragma unroll
            for (int m = 0; m < 4; ++m)
                #pragma unroll
                for (int n = 0; n < 4; ++n)
                    acc[m][n] = __builtin_amdgcn_mfma_f32_16x16x32_bf16(a[m], b[n], acc[m][n], 0, 0, 0);
        }
    }

    const int crow0 = (lane >> 4) * 4;
    #pragma unroll
    for (int m = 0; m < 4; ++m) {
        #pragma unroll
        for (int r = 0; r < 4; ++r) {
            int row = bm + m * 16 + crow0 + r;
            if (row >= M) continue;
            #pragma unroll
            for (int n = 0; n < 4; ++n) {
                int col = bn + n * 16 + lrow;
                size_t idx = (size_t)row * DH + col;
                float v = acc[m][n][r];
                if (EPI) {
                    v += bias[col];
                    v = fmaxf(v, 0.f);
                    v += bf2f(resid[idx]);
                }
                Cb[idx] = f2bf(v);
            }
        }
    }
}

// ------------------------------------------------------------------ launch
extern "C" void kernel_launch(void* const* d_in, const int* in_sizes, int n_in,
                              void* d_out, int out_size, void* d_ws, size_t ws_size,
                              hipStream_t stream) {
    const float* x    = (const float*)d_in[0];
    const int*   ei   = (const int*)d_in[1];
    const float* ea   = (const float*)d_in[2];
    const float* W0   = (const float*)d_in[3];
    const float* b0   = (const float*)d_in[4];
    const float* W1   = (const float*)d_in[5];
    const float* b1   = (const float*)d_in[6];
    const float* Wg   = (const float*)d_in[7];
    const float* bg   = (const float*)d_in[8];
    const float* a_src= (const float*)d_in[9];
    const float* a_dst= (const float*)d_in[10];
    const float* We   = (const float*)d_in[11];
    const float* a_e  = (const float*)d_in[12];
    const float* Ws   = (const float*)d_in[13];
    const float* Wn   = (const float*)d_in[14];
    const float* bm   = (const float*)d_in[15];
    float* out = (float*)d_out;

    const int N = in_sizes[0] / 3;
    const int E = in_sizes[1] / 2;
    const int Mpad = (N + 127) & ~127;
    const int* srcI = ei;
    const int* dstI = ei + E;

    char* p = (char*)d_ws;
    auto alloc = [&](size_t bytes) {
        void* r = (void*)p;
        p += (bytes + 255) & ~(size_t)255;
        return r;
    };
    size_t NBh = (size_t)Mpad * DH * sizeof(unsigned short);
    unsigned short* Hb0  = (unsigned short*)alloc(NBh);
    unsigned short* Hb1  = (unsigned short*)alloc(NBh);
    unsigned short* hgbf = (unsigned short*)alloc(NBh);   // reused as mean
    unsigned short* h1bf = (unsigned short*)alloc(NBh);
    unsigned short* Wt   = (unsigned short*)alloc((size_t)15 * DH * DH * sizeof(unsigned short));
    float* elogp = (float*)alloc((size_t)NLAYERS * E * sizeof(float));
    int*   csrc  = (int*)alloc((size_t)E * sizeof(int));
    int*   pos   = (int*)alloc((size_t)E * sizeof(int));
    int*   off   = (int*)alloc((size_t)(N + 1) * sizeof(int));
    int*   cnt   = (int*)alloc((size_t)N * sizeof(int));
    int*   cur   = (int*)alloc((size_t)N * sizeof(int));
    float* invd  = (float*)alloc((size_t)N * sizeof(float));
    float* ssrc  = (float*)alloc((size_t)N * sizeof(float));
    float* sdst  = (float*)alloc((size_t)N * sizeof(float));
    float* weae  = (float*)alloc((size_t)NLAYERS * DE * sizeof(float));
    const int NBLK = (N + SEG - 1) / SEG;  // 98 for N=50000 (<=128)
    int* part = (int*)alloc((size_t)NBLK * sizeof(int));
    int* base = (int*)alloc((size_t)NBLK * sizeof(int));

    const int EB = (E + 255) / 256;
    const int NB4 = (N + 3) / 4;
    const int MB = Mpad / 128;

    // ---- CSR build
    hipMemsetAsync(cnt, 0, (size_t)N * sizeof(int), stream);
    hipMemsetAsync(cur, 0, (size_t)N * sizeof(int), stream);
    k_count<<<EB, 256, 0, stream>>>(dstI, cnt, E);
    k_part<<<NBLK, SEG, 0, stream>>>(cnt, part, N);
    k_scanp<<<1, 128, 0, stream>>>(part, base, off, NBLK, N, E);
    k_emit<<<NBLK, SEG, 0, stream>>>(cnt, base, off, invd, N);
    k_fill<<<EB, 256, 0, stream>>>(srcI, dstI, off, cur, csrc, pos, E);

    // ---- h-independent edge terms (CSR-ordered), weight transposes
    k_we_ae<<<1, 256, 0, stream>>>(We, a_e, weae);
    k_elogit<<<EB, 256, 0, stream>>>(ea, weae, pos, elogp, E);
    k_wt<<<dim3(8, 8, 15), dim3(32, 8), 0, stream>>>(Wg, Ws, Wn, Wt);

    // ---- input projection
    k_lin0<<<N, DH, 0, stream>>>(x, W0, b0, Hb0, N);

    // ---- residual blocks
    unsigned short* Hcur = Hb0;
    unsigned short* Hnxt = Hb1;
    for (int l = 0; l < NLAYERS; ++l) {
        const unsigned short* Wgt = Wt + (size_t)l * DH * DH;
        const unsigned short* Wst = Wt + (size_t)(5 + l) * DH * DH;
        const unsigned short* Wnt = Wt + (size_t)(10 + l) * DH * DH;
        unsigned short* meanbf = hgbf;  // hg dead after k_attn

        k_gemm_mfma<0, 0><<<dim3(MB, 2), 256, 0, stream>>>(
            Hcur, Wgt, nullptr, nullptr, nullptr, nullptr, hgbf, N);
        k_dots<<<NB4, 256, 0, stream>>>(hgbf, a_src + (size_t)l * DH, a_dst + (size_t)l * DH,
                                        ssrc, sdst, N);
        k_attn<<<NB4, 256, 0, stream>>>(off, csrc, ssrc, sdst, elogp + (size_t)l * E,
                                        hgbf, bg + (size_t)l * DH, h1bf, N);
        k_mean<<<NB4, 256, 0, stream>>>(off, csrc, h1bf, invd, meanbf, N);
        k_gemm_mfma<1, 1><<<dim3(MB, 2), 256, 0, stream>>>(
            h1bf, Wst, meanbf, Wnt, bm + (size_t)l * DH, Hcur, Hnxt, N);

        unsigned short* tmp = Hcur; Hcur = Hnxt; Hnxt = tmp;
    }

    // ---- output projection
    k_out<<<NB4, 256, 0, stream>>>(Hcur, W1, b1, out, N);
}